// Round 6
// baseline (527.243 us; speedup 1.0000x reference)
//
#include <hip/hip_runtime.h>

typedef unsigned short ushort_t;
typedef unsigned long long u64;
typedef short short8 __attribute__((ext_vector_type(8)));
typedef float f32x4 __attribute__((ext_vector_type(4)));

#define B_   32
#define C_   64
#define T_   12
#define N_   1024
#define KS_  3
#define KC_  3072
#define RPB  768
#define NT_  48          // K-tiles of 64
#define BM_  192
#define LBUF 57344       // bytes per LDS buffer: A 192*64*2 (=24576) + B 256*64*2 (=32768)
#define ABYT 24576       // A region bytes (plane stride 12288)
#define BPLN 16384       // B plane stride

__device__ __forceinline__ float bf2f(ushort_t u) {
  union { unsigned u; float f; } v; v.u = ((unsigned)u) << 16; return v.f;
}
__device__ __forceinline__ ushort_t f2bf(float f) {
  union { float f; unsigned u; } v; v.f = f;
  unsigned r = v.u + 0x7FFFu + ((v.u >> 16) & 1u);
  return (ushort_t)(r >> 16);
}

__device__ __forceinline__ void gload16(const ushort_t* g, ushort_t* l) {
  __builtin_amdgcn_global_load_lds(
      (const __attribute__((address_space(1))) unsigned int*)g,
      (__attribute__((address_space(3))) unsigned int*)l, 16, 0, 0);
}

// ---------- prep: thA[l][k][o][i] = bf16(theta_l[i][o][k]) ----------
__global__ void prep_th(const float* __restrict__ th1, const float* __restrict__ th2,
                        ushort_t* __restrict__ out) {
  int id = blockIdx.x * 256 + threadIdx.x;          // 2*3*64*64 = 24576
  if (id >= 24576) return;
  int l = id / 12288, rem = id % 12288;
  int k = rem / 4096;
  int o = (rem >> 6) & 63;
  int i = rem & 63;
  const float* th = l ? th2 : th1;
  out[id] = f2bf(th[(i * 64 + o) * 3 + k]);
}

// ---------- prep: Bt[n][k*1024+m] = bf16(Lk[k][n][m]) ----------
__global__ void prep_bt(const float* __restrict__ Lk, ushort_t* __restrict__ Bt) {
  int id = blockIdx.x * 256 + threadIdx.x;
  int k = id >> 17, rem = id & 131071;
  int n = rem >> 7, mc = rem & 127;
  int m = mc << 3;
  const float* src = Lk + ((k * N_ + n) * N_ + m);
  float4 v0 = *(const float4*)src;
  float4 v1 = *(const float4*)(src + 4);
  short8 o8;
  o8[0] = (short)f2bf(v0.x); o8[1] = (short)f2bf(v0.y);
  o8[2] = (short)f2bf(v0.z); o8[3] = (short)f2bf(v0.w);
  o8[4] = (short)f2bf(v1.x); o8[5] = (short)f2bf(v1.y);
  o8[6] = (short)f2bf(v1.z); o8[7] = (short)f2bf(v1.w);
  *(short8*)&Bt[n * KC_ + k * N_ + m] = o8;
}

// ---------- MFMA channel mix: Y[(bl*12+t)*64+o][k*1024+m] = sum_i thA[k][o][i]*x[b,i,t,m] ----------
template<int IN_BF16>
__global__ __launch_bounds__(256, 2)
void mix_mfma(const void* __restrict__ in, const ushort_t* __restrict__ thA,
              ushort_t* __restrict__ Y, int b0) {
  const int bid = blockIdx.x;           // nb*48: [bt][mq]
  const int mq = bid & 3;
  const int bt = bid >> 2;              // bl*12 + t
  const int bl = bt / 12, t = bt % 12;
  const int b = b0 + bl;
  const int tid = threadIdx.x;
  const int wv = tid >> 6, lane = tid & 63;
  const int l15 = lane & 15, l4 = lane >> 4;
  const int m0 = mq * 256 + wv * 64;

  const ushort_t* xg_b = (const ushort_t*)in;
  const float*    xg_f = (const float*)in;

  // B-frags: bfr[mf][ks], lane: x[i = ks*32 + l4*8 + j][m0 + mf*16 + l15]
  short8 bfr[4][2];
  #pragma unroll
  for (int mf = 0; mf < 4; ++mf) {
    const int m = m0 + mf * 16 + l15;
    #pragma unroll
    for (int ks = 0; ks < 2; ++ks) {
      #pragma unroll
      for (int j = 0; j < 8; ++j) {
        const int i = ks * 32 + l4 * 8 + j;
        const size_t adr = ((size_t)(b * C_ + i) * T_ + t) * N_ + m;
        ushort_t v = IN_BF16 ? xg_b[adr] : f2bf(xg_f[adr]);
        bfr[mf][ks][j] = (short)v;
      }
    }
  }

  const size_t rbase = (size_t)(bt * C_);   // Y row base (bl*12+t)*64
  #pragma unroll
  for (int k = 0; k < 3; ++k) {
    short8 afr[4][2];
    #pragma unroll
    for (int of = 0; of < 4; ++of)
      #pragma unroll
      for (int ks = 0; ks < 2; ++ks)
        afr[of][ks] = *(const short8*)&thA[(size_t)(k * 64 + of * 16 + l15) * 64 + ks * 32 + l4 * 8];

    f32x4 acc[4][4] = {};
    #pragma unroll
    for (int ks = 0; ks < 2; ++ks)
      #pragma unroll
      for (int of = 0; of < 4; ++of)
        #pragma unroll
        for (int mf = 0; mf < 4; ++mf)
          acc[of][mf] = __builtin_amdgcn_mfma_f32_16x16x32_bf16(afr[of][ks], bfr[mf][ks], acc[of][mf], 0, 0, 0);

    #pragma unroll
    for (int of = 0; of < 4; ++of)
      #pragma unroll
      for (int mf = 0; mf < 4; ++mf)
        #pragma unroll
        for (int r = 0; r < 4; ++r) {
          const int o = of * 16 + l4 * 4 + r;
          Y[(rbase + o) * KC_ + k * N_ + m0 + mf * 16 + l15] = f2bf(acc[of][mf][r]);
        }
  }
}

// ---------- 192x256-tile batched-read GEMM: C = Y @ Bt^T, epilogue bias+residual+relu ----
// LDS per buffer: A [s:2][row:192][64B] (24576 B) then B [s:2][row:256][64B] (32768 B).
// Swizzle: stored col-byte = logical ^ (((row>>3)&1)<<5); applied on global source
// (write side, since global_load_lds dest must be linear) and on ds_read address.
// K-loop per iteration (2 barriers, counted vmcnt):
//   vmcnt(7)  -> barrier#1   all waves' tile-u stages landed (frag reads cross wave
//                            staging slices; vmcnt is per-wave, barrier globalizes it)
//   20 ds_read_b128 -> regs; lgkmcnt(0); sched_barrier -> barrier#2  buffer sealed
//   stage tile u+2 (7 gloads, writes buf[u&1] just sealed)  ;  48 MFMA from regs
// Slip analysis: a leading wave blocks at barrier#1(u+1) before stage(u+3); all
// concurrent windows touch distinct buffers. vmcnt(0) only at the final iteration.

#define STAGE_A(kt, j) gload16(gA##j + (size_t)(kt) * 64,                                   \
    (ushort_t*)(lp + (((kt) & 1) ? LBUF : 0) + (j) * 8192 + wofs))
#define STAGE_B(kt, j) gload16(gB##j + (size_t)(kt) * 64,                                   \
    (ushort_t*)(lp + (((kt) & 1) ? LBUF : 0) + ABYT + (j) * 8192 + wofs))

#define LD8(p) (*(const short8*)(p))

template<int RES_BF16>
__global__ __launch_bounds__(512, 2)
void gemm8p(const ushort_t* __restrict__ Y, const ushort_t* __restrict__ Bt,
            const void* __restrict__ res, const float* __restrict__ bias,
            ushort_t* __restrict__ outb, int batch0) {
  // bijective XCD swizzle; gridDim.x = 16*nb is always a multiple of 8
  const int nwg = gridDim.x;
  int orig = blockIdx.x;
  int q8 = nwg >> 3;
  int wg = (orig & 7) * q8 + (orig >> 3);
  const int mtile = wg >> 2, ntile = wg & 3;

  const int tid = threadIdx.x;
  const int wid = tid >> 6, lane = tid & 63;
  const int wm = wid >> 2, wn = wid & 3;
  const int l15 = lane & 15, l4 = lane >> 4;

  __shared__ ushort_t LDSU[LBUF];   // 114688 bytes total (2 buffers)
  char* lp = (char*)LDSU;

  const int row0 = mtile * BM_;
  const int n0 = ntile * 256;
  const int wofs = wid * 1024;

  // staging source pointers (per-lane, swizzle pre-applied on global col)
  const int lam = lane >> 2, lc = lane & 3;
  const ushort_t *gA0, *gA1, *gA2, *gB0, *gB1, *gB2, *gB3;
  {
    int p, s, row, colel;
    p = 0 * 128 + wid * 16 + lam; s = p >= 192 ? 1 : 0; row = p - s * 192;
    colel = (lc * 8) ^ (((row >> 3) & 1) << 4);
    gA0 = Y + (size_t)(row0 + row) * KC_ + s * 32 + colel;
    p = 1 * 128 + wid * 16 + lam; s = p >= 192 ? 1 : 0; row = p - s * 192;
    colel = (lc * 8) ^ (((row >> 3) & 1) << 4);
    gA1 = Y + (size_t)(row0 + row) * KC_ + s * 32 + colel;
    p = 2 * 128 + wid * 16 + lam; s = p >= 192 ? 1 : 0; row = p - s * 192;
    colel = (lc * 8) ^ (((row >> 3) & 1) << 4);
    gA2 = Y + (size_t)(row0 + row) * KC_ + s * 32 + colel;
    p = 0 * 128 + wid * 16 + lam; s = p >> 8; row = p & 255;
    colel = (lc * 8) ^ (((row >> 3) & 1) << 4);
    gB0 = Bt + (size_t)(n0 + row) * KC_ + s * 32 + colel;
    p = 1 * 128 + wid * 16 + lam; s = p >> 8; row = p & 255;
    colel = (lc * 8) ^ (((row >> 3) & 1) << 4);
    gB1 = Bt + (size_t)(n0 + row) * KC_ + s * 32 + colel;
    p = 2 * 128 + wid * 16 + lam; s = p >> 8; row = p & 255;
    colel = (lc * 8) ^ (((row >> 3) & 1) << 4);
    gB2 = Bt + (size_t)(n0 + row) * KC_ + s * 32 + colel;
    p = 3 * 128 + wid * 16 + lam; s = p >> 8; row = p & 255;
    colel = (lc * 8) ^ (((row >> 3) & 1) << 4);
    gB3 = Bt + (size_t)(n0 + row) * KC_ + s * 32 + colel;
  }

  // read-side lane byte bases (swizzle XOR on col)
  const int swz = ((l15 >> 3) & 1) << 5;
  const int a_base = (wm * 16 + l15) * 64 + ((l4 * 16) ^ swz);
  const int b_base = ABYT + (wn * 16 + l15) * 64 + ((l4 * 16) ^ swz);

  // prologue: stage tiles 0 and 1 (7 each); iter 0's vmcnt(7)+barrier waits tile 0
  STAGE_B(0, 0); STAGE_B(0, 1); STAGE_B(0, 2); STAGE_B(0, 3);
  STAGE_A(0, 0); STAGE_A(0, 1); STAGE_A(0, 2);
  STAGE_B(1, 0); STAGE_B(1, 1); STAGE_B(1, 2); STAGE_B(1, 3);
  STAGE_A(1, 0); STAGE_A(1, 1); STAGE_A(1, 2);

  f32x4 acc[6][4] = {};

  for (int u = 0; u < NT_; ++u) {
    const char* abp = lp + ((u & 1) ? LBUF : 0) + a_base;
    const char* bbp = lp + ((u & 1) ? LBUF : 0) + b_base;

    // barrier#1: tile u landed on ALL waves' slices
    if (u < NT_ - 1) {
      asm volatile("s_waitcnt vmcnt(7)" ::: "memory");
    } else {
      asm volatile("s_waitcnt vmcnt(0)" ::: "memory");
    }
    __builtin_amdgcn_s_barrier();
    __builtin_amdgcn_sched_barrier(0);

    // batched fragment reads for the whole K-tile
    short8 Af[2][6], Bf[2][4];
    #pragma unroll
    for (int s = 0; s < 2; ++s)
      #pragma unroll
      for (int m = 0; m < 6; ++m)
        Af[s][m] = LD8(abp + s * 12288 + m * 2048);
    #pragma unroll
    for (int s = 0; s < 2; ++s)
      #pragma unroll
      for (int n = 0; n < 4; ++n)
        Bf[s][n] = LD8(bbp + s * BPLN + n * 4096);

    asm volatile("s_waitcnt lgkmcnt(0)" ::: "memory");
    __builtin_amdgcn_sched_barrier(0);
    __builtin_amdgcn_s_barrier();     // barrier#2: buf[u&1] sealed
    __builtin_amdgcn_sched_barrier(0);

    if (u + 2 < NT_) {
      STAGE_B(u + 2, 0); STAGE_B(u + 2, 1); STAGE_B(u + 2, 2); STAGE_B(u + 2, 3);
      STAGE_A(u + 2, 0); STAGE_A(u + 2, 1); STAGE_A(u + 2, 2);
    }

    __builtin_amdgcn_s_setprio(1);
    #pragma unroll
    for (int s = 0; s < 2; ++s)
      #pragma unroll
      for (int m = 0; m < 6; ++m)
        #pragma unroll
        for (int n = 0; n < 4; ++n)
          acc[m][n] = __builtin_amdgcn_mfma_f32_16x16x32_bf16(Af[s][m], Bf[s][n], acc[m][n], 0, 0, 0);
    __builtin_amdgcn_s_setprio(0);
  }

  // epilogue: bias + residual + relu, bf16 store
  const float*    resf = (const float*)res;
  const ushort_t* resb = (const ushort_t*)res;
  const int gb = batch0 + (mtile >> 2);
  const int rowb0 = (mtile & 3) * BM_;
  const int colb = n0 + wn * 16 + l15;
  #pragma unroll
  for (int mf = 0; mf < 6; ++mf) {
    #pragma unroll
    for (int r = 0; r < 4; ++r) {
      int rl = mf * 32 + wm * 16 + l4 * 4 + r;
      int rowb = rowb0 + rl;
      int t = rowb >> 6, o = rowb & 63;
      float bs = bias[o];
      size_t base = ((size_t)(gb * C_ + o) * T_ + t) * N_;
      #pragma unroll
      for (int nf = 0; nf < 4; ++nf) {
        int col = colb + nf * 64;
        float rv = RES_BF16 ? bf2f(resb[base + col]) : resf[base + col];
        float v = acc[mf][nf][r] + bs + rv;
        v = fmaxf(v, 0.0f);
        outb[base + col] = f2bf(v);
      }
    }
  }
}

// ---------- FC: out[b,t,n,o2] = sum_o fw[o2,o]*x2[b,o,t,n] + fb[o2] ----------
__global__ __launch_bounds__(256, 2)
void fc_kernel(const ushort_t* __restrict__ x2, const float* __restrict__ fw,
               const float* __restrict__ fb, float* __restrict__ out) {
  int bid = blockIdx.x;
  int nt = bid & 15, btid = bid >> 4;
  int t = btid % 12, b = btid / 12;
  int n0 = nt << 6;
  int tid = threadIdx.x;
  __shared__ float xt[64 * 64];
  __shared__ float wl[64 * 64];
  #pragma unroll
  for (int j = 0; j < 2; ++j) {
    int c = tid + j * 256;
    int row = c >> 3, col = (c & 7) << 3;
    short8 v = *(const short8*)&x2[((b * C_ + row) * T_ + t) * N_ + n0 + col];
    #pragma unroll
    for (int q = 0; q < 8; ++q) xt[row * 64 + col + q] = bf2f((ushort_t)v[q]);
  }
  #pragma unroll
  for (int j = 0; j < 4; ++j) {
    int c = tid + j * 256;
    int o2 = c >> 4, o4 = (c & 15) << 2;
    float4 v = *(const float4*)&fw[o2 * 64 + o4];
    wl[(o4 + 0) * 64 + o2] = v.x; wl[(o4 + 1) * 64 + o2] = v.y;
    wl[(o4 + 2) * 64 + o2] = v.z; wl[(o4 + 3) * 64 + o2] = v.w;
  }
  __syncthreads();
  int p = tid & 31, ng = tid >> 5;
  float a0[8] = {}, a1[8] = {};
  for (int o = 0; o < 64; ++o) {
    float w0 = wl[o * 64 + p], w1 = wl[o * 64 + p + 32];
    float4 xa = *(const float4*)&xt[o * 64 + ng * 8];
    float4 xb = *(const float4*)&xt[o * 64 + ng * 8 + 4];
    float xv[8] = {xa.x, xa.y, xa.z, xa.w, xb.x, xb.y, xb.z, xb.w};
    #pragma unroll
    for (int j = 0; j < 8; ++j) { a0[j] = fmaf(w0, xv[j], a0[j]); a1[j] = fmaf(w1, xv[j], a1[j]); }
  }
  float fb0 = fb[p], fb1 = fb[p + 32];
  int obase = (b * T_ + t) * N_ + n0 + ng * 8;
  #pragma unroll
  for (int j = 0; j < 8; ++j) {
    out[(obase + j) * 64 + p]      = a0[j] + fb0;
    out[(obase + j) * 64 + p + 32] = a1[j] + fb1;
  }
}

extern "C" void kernel_launch(void* const* d_in, const int* in_sizes, int n_in,
                              void* d_out, int out_size, void* d_ws, size_t ws_size,
                              hipStream_t stream) {
  const float* x   = (const float*)d_in[0];
  const float* Lk  = (const float*)d_in[1];
  const float* th1 = (const float*)d_in[2];
  const float* b1  = (const float*)d_in[3];
  const float* th2 = (const float*)d_in[4];
  const float* b2  = (const float*)d_in[5];
  const float* fcw = (const float*)d_in[6];
  const float* fcb = (const float*)d_in[7];

  char* ws = (char*)d_ws;
  size_t off = 0;
  auto alloc = [&](size_t bytes) { size_t p = off; off += (bytes + 255) & ~(size_t)255; return p; };
  size_t oBt = alloc((size_t)KC_ * N_ * 2);
  size_t oTh = alloc((size_t)2 * 3 * 64 * 64 * 2);
  size_t oX2 = alloc((size_t)B_ * C_ * T_ * N_ * 2);
  size_t perB = (size_t)RPB * KC_ * 2;
  size_t avail = ws_size > off ? ws_size - off : 0;
  int NB = (int)(avail / perB);
  if (NB > B_) NB = B_;
  if (NB < 1) NB = 1;

  ushort_t* Bt = (ushort_t*)(ws + oBt);
  ushort_t* Th = (ushort_t*)(ws + oTh);
  ushort_t* X2 = (ushort_t*)(ws + oX2);
  ushort_t* Yb = (ushort_t*)(ws + off);
  ushort_t* X1 = (ushort_t*)d_out;

  prep_th<<<96, 256, 0, stream>>>(th1, th2, Th);
  prep_bt<<<1536, 256, 0, stream>>>(Lk, Bt);

  for (int b0 = 0; b0 < B_; b0 += NB) {
    int nb = (b0 + NB <= B_) ? NB : (B_ - b0);
    mix_mfma<0><<<nb * 48, 256, 0, stream>>>((const void*)x, Th, Yb, b0);
    gemm8p<0><<<dim3(16 * nb), 512, 0, stream>>>(Yb, Bt, (const void*)x, b1, X1, b0);
  }
  for (int b0 = 0; b0 < B_; b0 += NB) {
    int nb = (b0 + NB <= B_) ? NB : (B_ - b0);
    mix_mfma<1><<<nb * 48, 256, 0, stream>>>((const void*)X1, Th + 12288, Yb, b0);
    gemm8p<1><<<dim3(16 * nb), 512, 0, stream>>>(Yb, Bt, (const void*)X1, b2, X2, b0);
  }
  fc_kernel<<<32 * 12 * 16, 256, 0, stream>>>(X2, fcw, fcb, (float*)d_out);
}

// Round 7
// 504.484 us; speedup vs baseline: 1.0451x; 1.0451x over previous
//
#include <hip/hip_runtime.h>

typedef unsigned short ushort_t;
typedef unsigned long long u64;
typedef short short8 __attribute__((ext_vector_type(8)));
typedef float f32x4 __attribute__((ext_vector_type(4)));

#define B_   32
#define C_   64
#define T_   12
#define N_   1024
#define KS_  3
#define KC_  3072
#define RPB  768
#define NT_  48          // K-tiles of 64
#define BM_  192
#define LBUF 57344       // bytes per LDS buffer: A 192*64*2 (=24576) + B 256*64*2 (=32768)
#define ABYT 24576       // A region bytes
#define BPLN 16384       // B plane stride

__device__ __forceinline__ float bf2f(ushort_t u) {
  union { unsigned u; float f; } v; v.u = ((unsigned)u) << 16; return v.f;
}
__device__ __forceinline__ ushort_t f2bf(float f) {
  union { float f; unsigned u; } v; v.f = f;
  unsigned r = v.u + 0x7FFFu + ((v.u >> 16) & 1u);
  return (ushort_t)(r >> 16);
}

__device__ __forceinline__ void gload16(const ushort_t* g, ushort_t* l) {
  __builtin_amdgcn_global_load_lds(
      (const __attribute__((address_space(1))) unsigned int*)g,
      (__attribute__((address_space(3))) unsigned int*)l, 16, 0, 0);
}

// ---------- prep: thA[l][k][o][i] = bf16(theta_l[i][o][k]) ----------
__global__ void prep_th(const float* __restrict__ th1, const float* __restrict__ th2,
                        ushort_t* __restrict__ out) {
  int id = blockIdx.x * 256 + threadIdx.x;          // 2*3*64*64 = 24576
  if (id >= 24576) return;
  int l = id / 12288, rem = id % 12288;
  int k = rem / 4096;
  int o = (rem >> 6) & 63;
  int i = rem & 63;
  const float* th = l ? th2 : th1;
  out[id] = f2bf(th[(i * 64 + o) * 3 + k]);
}

// ---------- prep: Bt[n][k*1024+m] = bf16(Lk[k][n][m]) ----------
__global__ void prep_bt(const float* __restrict__ Lk, ushort_t* __restrict__ Bt) {
  int id = blockIdx.x * 256 + threadIdx.x;
  int k = id >> 17, rem = id & 131071;
  int n = rem >> 7, mc = rem & 127;
  int m = mc << 3;
  const float* src = Lk + ((k * N_ + n) * N_ + m);
  float4 v0 = *(const float4*)src;
  float4 v1 = *(const float4*)(src + 4);
  short8 o8;
  o8[0] = (short)f2bf(v0.x); o8[1] = (short)f2bf(v0.y);
  o8[2] = (short)f2bf(v0.z); o8[3] = (short)f2bf(v0.w);
  o8[4] = (short)f2bf(v1.x); o8[5] = (short)f2bf(v1.y);
  o8[6] = (short)f2bf(v1.z); o8[7] = (short)f2bf(v1.w);
  *(short8*)&Bt[n * KC_ + k * N_ + m] = o8;
}

// ---------- MFMA channel mix ----------
template<int IN_BF16>
__global__ __launch_bounds__(256, 2)
void mix_mfma(const void* __restrict__ in, const ushort_t* __restrict__ thA,
              ushort_t* __restrict__ Y, int b0) {
  const int bid = blockIdx.x;           // nb*48: [bt][mq]
  const int mq = bid & 3;
  const int bt = bid >> 2;              // bl*12 + t
  const int bl = bt / 12, t = bt % 12;
  const int b = b0 + bl;
  const int tid = threadIdx.x;
  const int wv = tid >> 6, lane = tid & 63;
  const int l15 = lane & 15, l4 = lane >> 4;
  const int m0 = mq * 256 + wv * 64;

  const ushort_t* xg_b = (const ushort_t*)in;
  const float*    xg_f = (const float*)in;

  short8 bfr[4][2];
  #pragma unroll
  for (int mf = 0; mf < 4; ++mf) {
    const int m = m0 + mf * 16 + l15;
    #pragma unroll
    for (int ks = 0; ks < 2; ++ks) {
      #pragma unroll
      for (int j = 0; j < 8; ++j) {
        const int i = ks * 32 + l4 * 8 + j;
        const size_t adr = ((size_t)(b * C_ + i) * T_ + t) * N_ + m;
        ushort_t v = IN_BF16 ? xg_b[adr] : f2bf(xg_f[adr]);
        bfr[mf][ks][j] = (short)v;
      }
    }
  }

  const size_t rbase = (size_t)(bt * C_);
  #pragma unroll
  for (int k = 0; k < 3; ++k) {
    short8 afr[4][2];
    #pragma unroll
    for (int of = 0; of < 4; ++of)
      #pragma unroll
      for (int ks = 0; ks < 2; ++ks)
        afr[of][ks] = *(const short8*)&thA[(size_t)(k * 64 + of * 16 + l15) * 64 + ks * 32 + l4 * 8];

    f32x4 acc[4][4] = {};
    #pragma unroll
    for (int ks = 0; ks < 2; ++ks)
      #pragma unroll
      for (int of = 0; of < 4; ++of)
        #pragma unroll
        for (int mf = 0; mf < 4; ++mf)
          acc[of][mf] = __builtin_amdgcn_mfma_f32_16x16x32_bf16(afr[of][ks], bfr[mf][ks], acc[of][mf], 0, 0, 0);

    #pragma unroll
    for (int of = 0; of < 4; ++of)
      #pragma unroll
      for (int mf = 0; mf < 4; ++mf)
        #pragma unroll
        for (int r = 0; r < 4; ++r) {
          const int o = of * 16 + l4 * 4 + r;
          Y[(rbase + o) * KC_ + k * N_ + m0 + mf * 16 + l15] = f2bf(acc[of][mf][r]);
        }
  }
}

// ---------- 192x256-tile phased GEMM with depth-1 fragment read-ahead ----------
// r4 stage/barrier schedule kept; each phase issues NEXT phase's ds_reads then
// MFMAs the pre-fetched current fragments (reg double-buffer aA/aB, bS0/bS1).
// Region-liveness ledger re-verified with shifted reads (see analysis).

#define MFMA12G(g, A, Bv)                                                                       \
  acc[3*(g)+0][0] = __builtin_amdgcn_mfma_f32_16x16x32_bf16(A[0], Bv[0], acc[3*(g)+0][0],0,0,0); \
  acc[3*(g)+0][1] = __builtin_amdgcn_mfma_f32_16x16x32_bf16(A[0], Bv[1], acc[3*(g)+0][1],0,0,0); \
  acc[3*(g)+0][2] = __builtin_amdgcn_mfma_f32_16x16x32_bf16(A[0], Bv[2], acc[3*(g)+0][2],0,0,0); \
  acc[3*(g)+0][3] = __builtin_amdgcn_mfma_f32_16x16x32_bf16(A[0], Bv[3], acc[3*(g)+0][3],0,0,0); \
  acc[3*(g)+1][0] = __builtin_amdgcn_mfma_f32_16x16x32_bf16(A[1], Bv[0], acc[3*(g)+1][0],0,0,0); \
  acc[3*(g)+1][1] = __builtin_amdgcn_mfma_f32_16x16x32_bf16(A[1], Bv[1], acc[3*(g)+1][1],0,0,0); \
  acc[3*(g)+1][2] = __builtin_amdgcn_mfma_f32_16x16x32_bf16(A[1], Bv[2], acc[3*(g)+1][2],0,0,0); \
  acc[3*(g)+1][3] = __builtin_amdgcn_mfma_f32_16x16x32_bf16(A[1], Bv[3], acc[3*(g)+1][3],0,0,0); \
  acc[3*(g)+2][0] = __builtin_amdgcn_mfma_f32_16x16x32_bf16(A[2], Bv[0], acc[3*(g)+2][0],0,0,0); \
  acc[3*(g)+2][1] = __builtin_amdgcn_mfma_f32_16x16x32_bf16(A[2], Bv[1], acc[3*(g)+2][1],0,0,0); \
  acc[3*(g)+2][2] = __builtin_amdgcn_mfma_f32_16x16x32_bf16(A[2], Bv[2], acc[3*(g)+2][2],0,0,0); \
  acc[3*(g)+2][3] = __builtin_amdgcn_mfma_f32_16x16x32_bf16(A[2], Bv[3], acc[3*(g)+2][3],0,0,0);

#define STAGE_A(kt, j) gload16(gA##j + (size_t)(kt) * 64,                                   \
    (ushort_t*)(lp + (((kt) & 1) ? LBUF : 0) + (j) * 8192 + wofs))
#define STAGE_B(kt, j) gload16(gB##j + (size_t)(kt) * 64,                                   \
    (ushort_t*)(lp + (((kt) & 1) ? LBUF : 0) + ABYT + (j) * 8192 + wofs))

#define LD8(p) (*(const short8*)(p))

template<int RES_BF16>
__global__ __launch_bounds__(512, 2)
void gemm8p(const ushort_t* __restrict__ Y, const ushort_t* __restrict__ Bt,
            const void* __restrict__ res, const float* __restrict__ bias,
            ushort_t* __restrict__ outb, int batch0) {
  // bijective XCD swizzle; gridDim.x = 16*nb is always a multiple of 8
  const int nwg = gridDim.x;
  int orig = blockIdx.x;
  int q8 = nwg >> 3;
  int wg = (orig & 7) * q8 + (orig >> 3);
  const int mtile = wg >> 2, ntile = wg & 3;

  const int tid = threadIdx.x;
  const int wid = tid >> 6, lane = tid & 63;
  const int wm = wid >> 2, wn = wid & 3;
  const int l15 = lane & 15, l4 = lane >> 4;

  __shared__ ushort_t LDSU[LBUF];   // 114688 bytes total (2 buffers)
  char* lp = (char*)LDSU;

  const int row0 = mtile * BM_;
  const int n0 = ntile * 256;
  const int wofs = wid * 1024;

  // staging source pointers (per-lane, swizzle pre-applied on global col)
  const int lam = lane >> 2, lc = lane & 3;
  const ushort_t *gA0, *gA1, *gA2, *gB0, *gB1, *gB2, *gB3;
  {
    int p, s, row, colel;
    p = 0 * 128 + wid * 16 + lam; s = p >= 192 ? 1 : 0; row = p - s * 192;
    colel = (lc * 8) ^ (((row >> 3) & 1) << 4);
    gA0 = Y + (size_t)(row0 + row) * KC_ + s * 32 + colel;
    p = 1 * 128 + wid * 16 + lam; s = p >= 192 ? 1 : 0; row = p - s * 192;
    colel = (lc * 8) ^ (((row >> 3) & 1) << 4);
    gA1 = Y + (size_t)(row0 + row) * KC_ + s * 32 + colel;
    p = 2 * 128 + wid * 16 + lam; s = p >= 192 ? 1 : 0; row = p - s * 192;
    colel = (lc * 8) ^ (((row >> 3) & 1) << 4);
    gA2 = Y + (size_t)(row0 + row) * KC_ + s * 32 + colel;
    p = 0 * 128 + wid * 16 + lam; s = p >> 8; row = p & 255;
    colel = (lc * 8) ^ (((row >> 3) & 1) << 4);
    gB0 = Bt + (size_t)(n0 + row) * KC_ + s * 32 + colel;
    p = 1 * 128 + wid * 16 + lam; s = p >> 8; row = p & 255;
    colel = (lc * 8) ^ (((row >> 3) & 1) << 4);
    gB1 = Bt + (size_t)(n0 + row) * KC_ + s * 32 + colel;
    p = 2 * 128 + wid * 16 + lam; s = p >> 8; row = p & 255;
    colel = (lc * 8) ^ (((row >> 3) & 1) << 4);
    gB2 = Bt + (size_t)(n0 + row) * KC_ + s * 32 + colel;
    p = 3 * 128 + wid * 16 + lam; s = p >> 8; row = p & 255;
    colel = (lc * 8) ^ (((row >> 3) & 1) << 4);
    gB3 = Bt + (size_t)(n0 + row) * KC_ + s * 32 + colel;
  }

  // read-side lane byte bases (swizzle XOR on col)
  const int swz = ((l15 >> 3) & 1) << 5;
  const int a_base = (wm * 16 + l15) * 64 + ((l4 * 16) ^ swz);
  const int b_base = ABYT + (wn * 16 + l15) * 64 + ((l4 * 16) ^ swz);

  // prologue: tile0 fully, tile1 minus A2 (13 units); vmcnt(6) -> tile0 landed
  STAGE_B(0, 0); STAGE_B(0, 1); STAGE_B(0, 2); STAGE_B(0, 3);
  STAGE_A(0, 0); STAGE_A(0, 1); STAGE_A(0, 2);
  STAGE_B(1, 0); STAGE_B(1, 1); STAGE_B(1, 2); STAGE_B(1, 3);
  STAGE_A(1, 0); STAGE_A(1, 1);
  asm volatile("s_waitcnt vmcnt(6)" ::: "memory");
  __builtin_amdgcn_s_barrier();
  __builtin_amdgcn_sched_barrier(0);

  f32x4 acc[6][4] = {};
  short8 aA[3], aB[3], bS0[4], bS1[4];

  // pre-read G0(0): A s0 m0-2 + B s0
  {
    const char* abp = lp + a_base;
    const char* bbp = lp + b_base;
    aA[0] = LD8(abp);          aA[1] = LD8(abp + 2048);   aA[2] = LD8(abp + 4096);
    bS0[0] = LD8(bbp);         bS0[1] = LD8(bbp + 4096);
    bS0[2] = LD8(bbp + 8192);  bS0[3] = LD8(bbp + 12288);
  }

  for (int u = 0; u < NT_; ++u) {
    const char* abp = lp + ((u & 1) ? LBUF : 0) + a_base;
    const char* bbp = lp + ((u & 1) ? LBUF : 0) + b_base;
    const char* abn = lp + ((u & 1) ? 0 : LBUF) + a_base;   // next tile's buffer
    const char* bbn = lp + ((u & 1) ? 0 : LBUF) + b_base;

    { // phase 0: MFMA(G0: aA x bS0) ; read G1 (A s0 m3-5) ; stage A2(u+1)
      if (u + 1 < NT_) STAGE_A(u + 1, 2);
      __builtin_amdgcn_s_barrier();
      __builtin_amdgcn_sched_barrier(0);
      aB[0] = LD8(abp + 6144); aB[1] = LD8(abp + 8192); aB[2] = LD8(abp + 10240);
      __builtin_amdgcn_sched_barrier(0);
      __builtin_amdgcn_s_setprio(1);
      MFMA12G(0, aA, bS0)
      __builtin_amdgcn_s_setprio(0);
      __builtin_amdgcn_s_barrier();
    }
    { // phase 1: MFMA(G1: aB x bS0) ; read G2 (A s1 m0-2 + B s1) ; stage B0,B1(u+2)
      if (u + 2 < NT_) { STAGE_B(u + 2, 0); STAGE_B(u + 2, 1); }
      __builtin_amdgcn_s_barrier();
      __builtin_amdgcn_sched_barrier(0);
      aA[0] = LD8(abp + 12288);         aA[1] = LD8(abp + 12288 + 2048);
      aA[2] = LD8(abp + 12288 + 4096);
      bS1[0] = LD8(bbp + BPLN);         bS1[1] = LD8(bbp + BPLN + 4096);
      bS1[2] = LD8(bbp + BPLN + 8192);  bS1[3] = LD8(bbp + BPLN + 12288);
      __builtin_amdgcn_sched_barrier(0);
      __builtin_amdgcn_s_setprio(1);
      MFMA12G(1, aB, bS0)
      __builtin_amdgcn_s_setprio(0);
      __builtin_amdgcn_s_barrier();
    }
    { // phase 2: MFMA(G2: aA x bS1) ; read G3 (A s1 m3-5)
      __builtin_amdgcn_s_barrier();
      __builtin_amdgcn_sched_barrier(0);
      aB[0] = LD8(abp + 12288 + 6144);
      aB[1] = LD8(abp + 12288 + 8192);
      aB[2] = LD8(abp + 12288 + 10240);
      __builtin_amdgcn_sched_barrier(0);
      __builtin_amdgcn_s_setprio(1);
      MFMA12G(0, aA, bS1)
      __builtin_amdgcn_s_setprio(0);
      __builtin_amdgcn_s_barrier();
    }
    { // phase 3: MFMA(G3: aB x bS1) ; stage B2,B3,A0,A1(u+2) ; counted vmcnt ;
      //          read G0(u+1) from next buffer (tile u+1 proven landed)
      if (u + 2 < NT_) {
        STAGE_B(u + 2, 2); STAGE_B(u + 2, 3);
        STAGE_A(u + 2, 0); STAGE_A(u + 2, 1);
        asm volatile("s_waitcnt vmcnt(6)" ::: "memory");  // tile u+1 complete
      } else if (u + 2 == NT_) {
        asm volatile("s_waitcnt vmcnt(0)" ::: "memory");  // drain for last tile
      }
      __builtin_amdgcn_s_barrier();
      __builtin_amdgcn_sched_barrier(0);
      if (u + 1 < NT_) {
        aA[0] = LD8(abn);          aA[1] = LD8(abn + 2048);   aA[2] = LD8(abn + 4096);
        bS0[0] = LD8(bbn);         bS0[1] = LD8(bbn + 4096);
        bS0[2] = LD8(bbn + 8192);  bS0[3] = LD8(bbn + 12288);
      }
      __builtin_amdgcn_sched_barrier(0);
      __builtin_amdgcn_s_setprio(1);
      MFMA12G(1, aB, bS1)
      __builtin_amdgcn_s_setprio(0);
      __builtin_amdgcn_s_barrier();
    }
  }

  // epilogue: bias + residual + relu, bf16 store
  const float*    resf = (const float*)res;
  const ushort_t* resb = (const ushort_t*)res;
  const int gb = batch0 + (mtile >> 2);
  const int rowb0 = (mtile & 3) * BM_;
  const int colb = n0 + wn * 16 + l15;
  #pragma unroll
  for (int mf = 0; mf < 6; ++mf) {
    #pragma unroll
    for (int r = 0; r < 4; ++r) {
      int rl = mf * 32 + wm * 16 + l4 * 4 + r;
      int rowb = rowb0 + rl;
      int t = rowb >> 6, o = rowb & 63;
      float bs = bias[o];
      size_t base = ((size_t)(gb * C_ + o) * T_ + t) * N_;
      #pragma unroll
      for (int nf = 0; nf < 4; ++nf) {
        int col = colb + nf * 64;
        float rv = RES_BF16 ? bf2f(resb[base + col]) : resf[base + col];
        float v = acc[mf][nf][r] + bs + rv;
        v = fmaxf(v, 0.0f);
        outb[base + col] = f2bf(v);
      }
    }
  }
}

// ---------- FC: out[b,t,n,o2] = sum_o fw[o2,o]*x2[b,o,t,n] + fb[o2] ----------
__global__ __launch_bounds__(256, 2)
void fc_kernel(const ushort_t* __restrict__ x2, const float* __restrict__ fw,
               const float* __restrict__ fb, float* __restrict__ out) {
  int bid = blockIdx.x;
  int nt = bid & 15, btid = bid >> 4;
  int t = btid % 12, b = btid / 12;
  int n0 = nt << 6;
  int tid = threadIdx.x;
  __shared__ float xt[64 * 64];
  __shared__ float wl[64 * 64];
  #pragma unroll
  for (int j = 0; j < 2; ++j) {
    int c = tid + j * 256;
    int row = c >> 3, col = (c & 7) << 3;
    short8 v = *(const short8*)&x2[((b * C_ + row) * T_ + t) * N_ + n0 + col];
    #pragma unroll
    for (int q = 0; q < 8; ++q) xt[row * 64 + col + q] = bf2f((ushort_t)v[q]);
  }
  #pragma unroll
  for (int j = 0; j < 4; ++j) {
    int c = tid + j * 256;
    int o2 = c >> 4, o4 = (c & 15) << 2;
    float4 v = *(const float4*)&fw[o2 * 64 + o4];
    wl[(o4 + 0) * 64 + o2] = v.x; wl[(o4 + 1) * 64 + o2] = v.y;
    wl[(o4 + 2) * 64 + o2] = v.z; wl[(o4 + 3) * 64 + o2] = v.w;
  }
  __syncthreads();
  int p = tid & 31, ng = tid >> 5;
  float a0[8] = {}, a1[8] = {};
  for (int o = 0; o < 64; ++o) {
    float w0 = wl[o * 64 + p], w1 = wl[o * 64 + p + 32];
    float4 xa = *(const float4*)&xt[o * 64 + ng * 8];
    float4 xb = *(const float4*)&xt[o * 64 + ng * 8 + 4];
    float xv[8] = {xa.x, xa.y, xa.z, xa.w, xb.x, xb.y, xb.z, xb.w};
    #pragma unroll
    for (int j = 0; j < 8; ++j) { a0[j] = fmaf(w0, xv[j], a0[j]); a1[j] = fmaf(w1, xv[j], a1[j]); }
  }
  float fb0 = fb[p], fb1 = fb[p + 32];
  int obase = (b * T_ + t) * N_ + n0 + ng * 8;
  #pragma unroll
  for (int j = 0; j < 8; ++j) {
    out[(obase + j) * 64 + p]      = a0[j] + fb0;
    out[(obase + j) * 64 + p + 32] = a1[j] + fb1;
  }
}

extern "C" void kernel_launch(void* const* d_in, const int* in_sizes, int n_in,
                              void* d_out, int out_size, void* d_ws, size_t ws_size,
                              hipStream_t stream) {
  const float* x   = (const float*)d_in[0];
  const float* Lk  = (const float*)d_in[1];
  const float* th1 = (const float*)d_in[2];
  const float* b1  = (const float*)d_in[3];
  const float* th2 = (const float*)d_in[4];
  const float* b2  = (const float*)d_in[5];
  const float* fcw = (const float*)d_in[6];
  const float* fcb = (const float*)d_in[7];

  char* ws = (char*)d_ws;
  size_t off = 0;
  auto alloc = [&](size_t bytes) { size_t p = off; off += (bytes + 255) & ~(size_t)255; return p; };
  size_t oBt = alloc((size_t)KC_ * N_ * 2);
  size_t oTh = alloc((size_t)2 * 3 * 64 * 64 * 2);
  size_t oX2 = alloc((size_t)B_ * C_ * T_ * N_ * 2);
  size_t perB = (size_t)RPB * KC_ * 2;
  size_t avail = ws_size > off ? ws_size - off : 0;
  int NB = (int)(avail / perB);
  if (NB > B_) NB = B_;
  if (NB < 1) NB = 1;

  ushort_t* Bt = (ushort_t*)(ws + oBt);
  ushort_t* Th = (ushort_t*)(ws + oTh);
  ushort_t* X2 = (ushort_t*)(ws + oX2);
  ushort_t* Yb = (ushort_t*)(ws + off);
  ushort_t* X1 = (ushort_t*)d_out;

  prep_th<<<96, 256, 0, stream>>>(th1, th2, Th);
  prep_bt<<<1536, 256, 0, stream>>>(Lk, Bt);

  for (int b0 = 0; b0 < B_; b0 += NB) {
    int nb = (b0 + NB <= B_) ? NB : (B_ - b0);
    mix_mfma<0><<<nb * 48, 256, 0, stream>>>((const void*)x, Th, Yb, b0);
    gemm8p<0><<<dim3(16 * nb), 512, 0, stream>>>(Yb, Bt, (const void*)x, b1, X1, b0);
  }
  for (int b0 = 0; b0 < B_; b0 += NB) {
    int nb = (b0 + NB <= B_) ? NB : (B_ - b0);
    mix_mfma<1><<<nb * 48, 256, 0, stream>>>((const void*)X1, Th + 12288, Yb, b0);
    gemm8p<1><<<dim3(16 * nb), 512, 0, stream>>>(Yb, Bt, (const void*)X1, b2, X2, b0);
  }
  fc_kernel<<<32 * 12 * 16, 256, 0, stream>>>(X2, fcw, fcb, (float*)d_out);
}